// Round 2
// baseline (669.051 us; speedup 1.0000x reference)
//
#include <hip/hip_runtime.h>
#include <hip/hip_bf16.h>

// Problem constants (from reference): memory [E, M, D] fp32
constexpr int E = 1024;
constexpr int M = 200;
constexpr int D = 512;
constexpr long long TOT = (long long)E * M * D;   // 104,857,600 floats
constexpr int PER_ENV4 = M * D / 4;                // 25,600 float4 per env
constexpr int PER_ROW4 = D / 4;                    // 128 float4 per row
constexpr float NOVELTY_THRESHOLD = 0.5f;

// One block per env. Thread 0 emits the updated counter; if the env accepts
// the new feature, all 128 threads overwrite the 2 KB target row.
__global__ __launch_bounds__(128) void reach_fixup(
    const float4* __restrict__ obs,     // [E*D/4]
    const float*  __restrict__ sim,     // [E]
    const int*    __restrict__ mask,    // [E]
    const int*    __restrict__ ridx,    // [E]
    float4*       __restrict__ out_mem, // [E*M*D/4] (already holds the copy)
    float*        __restrict__ out_mask // [E], written as float values
) {
    int e = blockIdx.x;
    int t = threadIdx.x;  // 0..127, one float4 of the row each

    int  mk   = mask[e];
    bool add  = sim[e] > NOVELTY_THRESHOLD;
    bool full = (mk == M);
    int  nm   = mk + (int)((!full) && add);

    if (t == 0) out_mask[e] = (float)nm;   // exact in fp32 for values <= 201

    if (add) {
        int idx = full ? ridx[e] : (nm - 1);   // nm>=1 here when !full
        out_mem[(long long)e * PER_ENV4 + (long long)idx * PER_ROW4 + t] =
            obs[e * PER_ROW4 + t];
    }
}

extern "C" void kernel_launch(void* const* d_in, const int* in_sizes, int n_in,
                              void* d_out, int out_size, void* d_ws, size_t ws_size,
                              hipStream_t stream) {
    const void*   mem  = d_in[0];
    const float4* obs  = (const float4*)d_in[1];
    const float*  sim  = (const float*)d_in[2];
    const int*    mask = (const int*)d_in[3];
    const int*    ridx = (const int*)d_in[4];

    float* out      = (float*)d_out;
    float* out_mask = out + TOT;   // mask tail starts after the memory bank

    // Bulk copy of the memory bank via the copy engine (graph-capturable).
    hipMemcpyAsync(out, mem, (size_t)TOT * sizeof(float),
                   hipMemcpyDeviceToDevice, stream);

    // Then overwrite at most one row per env + write the counters.
    reach_fixup<<<E, 128, 0, stream>>>(obs, sim, mask, ridx,
                                       (float4*)out, out_mask);
}